// Round 6
// baseline (452.306 us; speedup 1.0000x reference)
//
#include <hip/hip_runtime.h>

// SpMM: out[i,d] = sum_{e: rows[e]==i} vals[e] * x[cols[e], d]
// N=100000, E=1600000, DIM=32, fp32.
//
// Round 6: gather was stuck ~300us regardless of occupancy/MLP -> saturated
// random-line L2-miss path (x gather). Fixes:
//  - per-block counting sort of edges by col-tile (col>>14, 8 x 2MB tiles)
//    into LDS; co-resident blocks sweep tiles in phase -> x reads hit L2
//  - 8 lanes/edge float4 x reads: 8 edges/wave, 4-deep unroll = 32
//    outstanding lines per wave
//  - LDS accumulator stride 36 (pad +4) to spread atomic banks

#define N_NODES 100000
#define N_EDGES 1600000
#define DIM 32

#define BUCKET_ROWS 64
#define BUCKET_SHIFT 6
#define NBUCK ((N_NODES + BUCKET_ROWS - 1) / BUCKET_ROWS)   // 1563

#define ACC_STRIDE 36
#define LDS_ACC (BUCKET_ROWS * ACC_STRIDE)                  // 2304 floats

#define NTILE 8
#define TSHIFT 14          // 16384 cols/tile = 2MB of x
#define EBUF 1536          // per-bucket edge buffer (mean 1024, sigma ~32)

#define TILE 8192
#define NBLK ((N_EDGES + TILE - 1) / TILE)                  // 196
#define MATN (NBUCK * NBLK)                                 // 306348
#define SCANB 1024
#define NSCAN ((MATN + SCANB - 1) / SCANB)                  // 300

// ---- workspace layout (in ints) ----
#define WS_SCV   0                        // int2 per edge: [0, 3200000)
#define WS_MAT   3200000                  // 306348 (pad 306432)
#define WS_BSUM  3506432                  // 512
#define WS_TOTAL_INTS 3506944             // ~14.03 MB

// 1) per-block LDS histogram -> mat[b*NBLK + blk]
__global__ __launch_bounds__(256) void hist_kernel(
    const int* __restrict__ rows, int* __restrict__ mat)
{
    __shared__ int h[NBUCK];
    for (int i = threadIdx.x; i < NBUCK; i += 256) h[i] = 0;
    __syncthreads();
    const int base = blockIdx.x * TILE;
    for (int i = 0; i < TILE / 256; ++i) {
        int e = base + threadIdx.x + i * 256;
        if (e < N_EDGES) atomicAdd(&h[rows[e] >> BUCKET_SHIFT], 1);
    }
    __syncthreads();
    for (int b = threadIdx.x; b < NBUCK; b += 256)
        mat[b * NBLK + blockIdx.x] = h[b];
}

// 2a) block-wise exclusive scan of mat, emit block sums
__global__ __launch_bounds__(SCANB) void scanA_kernel(
    int* __restrict__ mat, int* __restrict__ bsum)
{
    __shared__ int lds[SCANB];
    int i = blockIdx.x * SCANB + threadIdx.x;
    int v = (i < MATN) ? mat[i] : 0;
    lds[threadIdx.x] = v;
    __syncthreads();
    for (int off = 1; off < SCANB; off <<= 1) {
        int t = (threadIdx.x >= off) ? lds[threadIdx.x - off] : 0;
        __syncthreads();
        lds[threadIdx.x] += t;
        __syncthreads();
    }
    int incl = lds[threadIdx.x];
    if (i < MATN) mat[i] = incl - v;
    if (threadIdx.x == SCANB - 1) bsum[blockIdx.x] = incl;
}

// 2b) scan the 300 block sums
__global__ __launch_bounds__(512) void scanB_kernel(int* __restrict__ bsum)
{
    __shared__ int lds[512];
    int v = (threadIdx.x < NSCAN) ? bsum[threadIdx.x] : 0;
    lds[threadIdx.x] = v;
    __syncthreads();
    for (int off = 1; off < 512; off <<= 1) {
        int t = (threadIdx.x >= off) ? lds[threadIdx.x - off] : 0;
        __syncthreads();
        lds[threadIdx.x] += t;
        __syncthreads();
    }
    if (threadIdx.x < NSCAN) bsum[threadIdx.x] = lds[threadIdx.x] - v;
}

// 2c) add block offsets
__global__ __launch_bounds__(SCANB) void scanC_kernel(
    int* __restrict__ mat, const int* __restrict__ bsum)
{
    int i = blockIdx.x * SCANB + threadIdx.x;
    if (i < MATN) mat[i] += bsum[blockIdx.x];
}

// 3) scatter: per-block LDS cursors; each (bucket,block) run owned by 1 block
__global__ __launch_bounds__(256) void scatter_kernel(
    const int* __restrict__ rows, const int* __restrict__ cols,
    const float* __restrict__ vals, const int* __restrict__ mat,
    int2* __restrict__ scv)
{
    __shared__ int cur[NBUCK];
    for (int b = threadIdx.x; b < NBUCK; b += 256)
        cur[b] = mat[b * NBLK + blockIdx.x];
    __syncthreads();
    const int base = blockIdx.x * TILE;
    for (int i = 0; i < TILE / 256; ++i) {
        int e = base + threadIdx.x + i * 256;
        if (e < N_EDGES) {
            int r = rows[e];
            int p = atomicAdd(&cur[r >> BUCKET_SHIFT], 1);
            int packed = ((r & (BUCKET_ROWS - 1)) << 17) | cols[e];
            scv[p] = make_int2(packed, __float_as_int(vals[e]));
        }
    }
}

// 4) gather: tile-sort edges in LDS, then 8-lane/edge float4 processing
__global__ __launch_bounds__(256) void gather_kernel(
    const int* __restrict__ mat, const int2* __restrict__ scv,
    const float* __restrict__ x, float4* __restrict__ out4)
{
    __shared__ float acc[LDS_ACC];
    __shared__ int2 ebuf[EBUF];
    __shared__ int tcur[NTILE];
    const int b = blockIdx.x;
    for (int i = threadIdx.x; i < LDS_ACC; i += 256) acc[i] = 0.f;
    if (threadIdx.x < NTILE) tcur[threadIdx.x] = 0;
    __syncthreads();

    const int beg = mat[b * NBLK];
    const int end = (b + 1 < NBUCK) ? mat[(b + 1) * NBLK] : N_EDGES;
    const int n = end - beg;
    const int nl = (n < EBUF) ? n : EBUF;

    // Phase A: tile histogram
    for (int i = threadIdx.x; i < nl; i += 256) {
        int2 cv = scv[beg + i];
        atomicAdd(&tcur[(cv.x & 0x1FFFF) >> TSHIFT], 1);
    }
    __syncthreads();
    if (threadIdx.x == 0) {
        int run = 0;
        for (int t = 0; t < NTILE; ++t) { int c = tcur[t]; tcur[t] = run; run += c; }
    }
    __syncthreads();
    // Phase B: counting-sort into ebuf by tile (scv re-read is L2-hot)
    for (int i = threadIdx.x; i < nl; i += 256) {
        int2 cv = scv[beg + i];
        int p = atomicAdd(&tcur[(cv.x & 0x1FFFF) >> TSHIFT], 1);
        ebuf[p] = cv;
    }
    __syncthreads();

    // Phase C: 8 lanes/edge, float4 x reads, 4-deep unroll (32 lines/wave)
    const float4* x4 = (const float4*)x;
    const int l = threadIdx.x & 7;    // float4 lane within row
    const int g = threadIdx.x >> 3;   // edge slot 0..31
    int e = g;
    for (; e + 96 < nl; e += 128) {
        int2 cv0 = ebuf[e];
        int2 cv1 = ebuf[e + 32];
        int2 cv2 = ebuf[e + 64];
        int2 cv3 = ebuf[e + 96];
        float4 xv0 = x4[(cv0.x & 0x1FFFF) * 8 + l];
        float4 xv1 = x4[(cv1.x & 0x1FFFF) * 8 + l];
        float4 xv2 = x4[(cv2.x & 0x1FFFF) * 8 + l];
        float4 xv3 = x4[(cv3.x & 0x1FFFF) * 8 + l];
        float v0 = __int_as_float(cv0.y), v1 = __int_as_float(cv1.y);
        float v2 = __int_as_float(cv2.y), v3 = __int_as_float(cv3.y);
        int a0 = (((unsigned)cv0.x) >> 17) * ACC_STRIDE + l * 4;
        int a1 = (((unsigned)cv1.x) >> 17) * ACC_STRIDE + l * 4;
        int a2 = (((unsigned)cv2.x) >> 17) * ACC_STRIDE + l * 4;
        int a3 = (((unsigned)cv3.x) >> 17) * ACC_STRIDE + l * 4;
        atomicAdd(&acc[a0 + 0], v0 * xv0.x); atomicAdd(&acc[a0 + 1], v0 * xv0.y);
        atomicAdd(&acc[a0 + 2], v0 * xv0.z); atomicAdd(&acc[a0 + 3], v0 * xv0.w);
        atomicAdd(&acc[a1 + 0], v1 * xv1.x); atomicAdd(&acc[a1 + 1], v1 * xv1.y);
        atomicAdd(&acc[a1 + 2], v1 * xv1.z); atomicAdd(&acc[a1 + 3], v1 * xv1.w);
        atomicAdd(&acc[a2 + 0], v2 * xv2.x); atomicAdd(&acc[a2 + 1], v2 * xv2.y);
        atomicAdd(&acc[a2 + 2], v2 * xv2.z); atomicAdd(&acc[a2 + 3], v2 * xv2.w);
        atomicAdd(&acc[a3 + 0], v3 * xv3.x); atomicAdd(&acc[a3 + 1], v3 * xv3.y);
        atomicAdd(&acc[a3 + 2], v3 * xv3.z); atomicAdd(&acc[a3 + 3], v3 * xv3.w);
    }
    for (; e < nl; e += 32) {
        int2 cv = ebuf[e];
        float4 xv = x4[(cv.x & 0x1FFFF) * 8 + l];
        float v = __int_as_float(cv.y);
        int a = (((unsigned)cv.x) >> 17) * ACC_STRIDE + l * 4;
        atomicAdd(&acc[a + 0], v * xv.x); atomicAdd(&acc[a + 1], v * xv.y);
        atomicAdd(&acc[a + 2], v * xv.z); atomicAdd(&acc[a + 3], v * xv.w);
    }
    // Phase D: overflow beyond EBUF (statistically never; correctness guard)
    for (int e2 = nl + g; e2 < n; e2 += 32) {
        int2 cv = scv[beg + e2];
        float4 xv = x4[(cv.x & 0x1FFFF) * 8 + l];
        float v = __int_as_float(cv.y);
        int a = (((unsigned)cv.x) >> 17) * ACC_STRIDE + l * 4;
        atomicAdd(&acc[a + 0], v * xv.x); atomicAdd(&acc[a + 1], v * xv.y);
        atomicAdd(&acc[a + 2], v * xv.z); atomicAdd(&acc[a + 3], v * xv.w);
    }
    __syncthreads();

    const int r0 = b * BUCKET_ROWS;
    const int nrows = min(BUCKET_ROWS, N_NODES - r0);
    const int nf4 = nrows * (DIM / 4);
    for (int i = threadIdx.x; i < nf4; i += 256) {
        int r = i >> 3, c = (i & 7) * 4;
        const float* a = &acc[r * ACC_STRIDE + c];
        out4[r0 * (DIM / 4) + i] = make_float4(a[0], a[1], a[2], a[3]);
    }
}

// ---- fallback (round-1 path) if ws too small ----
__global__ __launch_bounds__(256) void spmm_atomic_kernel(
    const int* __restrict__ rows, const int* __restrict__ cols,
    const float* __restrict__ vals, const float* __restrict__ x,
    float* __restrict__ out)
{
    long long idx = (long long)blockIdx.x * blockDim.x + threadIdx.x;
    if (idx >= (long long)N_EDGES * DIM) return;
    int e = (int)(idx >> 5);
    int d = (int)(idx & 31);
    atomicAdd(&out[(long long)rows[e] * DIM + d], vals[e] * x[(long long)cols[e] * DIM + d]);
}

extern "C" void kernel_launch(void* const* d_in, const int* in_sizes, int n_in,
                              void* d_out, int out_size, void* d_ws, size_t ws_size,
                              hipStream_t stream) {
    const int*   A_rows = (const int*)d_in[0];
    const int*   A_cols = (const int*)d_in[1];
    const float* A_vals = (const float*)d_in[2];
    const float* x      = (const float*)d_in[3];
    float*       out    = (float*)d_out;

    if (ws_size < (size_t)WS_TOTAL_INTS * sizeof(int)) {
        hipMemsetAsync(out, 0, (size_t)out_size * sizeof(float), stream);
        long long total = (long long)N_EDGES * DIM;
        spmm_atomic_kernel<<<(unsigned)((total + 255) / 256), 256, 0, stream>>>(
            A_rows, A_cols, A_vals, x, out);
        return;
    }

    int*  ws   = (int*)d_ws;
    int2* scv  = (int2*)(ws + WS_SCV);
    int*  mat  = ws + WS_MAT;
    int*  bsum = ws + WS_BSUM;

    hist_kernel <<<NBLK, 256, 0, stream>>>(A_rows, mat);
    scanA_kernel<<<NSCAN, SCANB, 0, stream>>>(mat, bsum);
    scanB_kernel<<<1, 512, 0, stream>>>(bsum);
    scanC_kernel<<<NSCAN, SCANB, 0, stream>>>(mat, bsum);
    scatter_kernel<<<NBLK, 256, 0, stream>>>(A_rows, A_cols, A_vals, mat, scv);
    gather_kernel<<<NBUCK, 256, 0, stream>>>(mat, scv, x, (float4*)out);
}